// Round 10
// baseline (340.463 us; speedup 1.0000x reference)
//
#include <hip/hip_runtime.h>
#include <math.h>

#define EPSQ 1e-5

typedef int v4i  __attribute__((ext_vector_type(4)));
typedef int v16i __attribute__((ext_vector_type(16)));

// ================= weight stats: partial sums, f64 =================
__device__ void bstat(const float* __restrict__ w, int cnt, double2* dst, int divn) {
    __shared__ double ls[4], la[4];
    int t = threadIdx.x;
    double s = 0.0, a = 0.0;
    const float4* w4 = (const float4*)w;
    int nv = cnt >> 2;
    for (int i = t; i < nv; i += 256) {
        float4 v = w4[i];
        s += (double)v.x + (double)v.y + (double)v.z + (double)v.w;
        a += fabs((double)v.x) + fabs((double)v.y) + fabs((double)v.z) + fabs((double)v.w);
    }
    for (int o = 32; o; o >>= 1) { s += __shfl_down(s, o); a += __shfl_down(a, o); }
    if ((t & 63) == 0) { ls[t >> 6] = s; la[t >> 6] = a; }
    __syncthreads();
    if (t == 0) {
        for (int i = 1; i < 4; i++) { s += ls[i]; a += la[i]; }
        if (divn > 0) { dst->x = s / divn; dst->y = a / divn; }
        else          { dst->x = s;        dst->y = a; }
    }
}

// grid = 40 blocks: 0:c1 1:c1b 2:c2 3:fcl | 4-7:fc1/4 | 8-23:fc2/16 | 24-39:fc3/16
__global__ __launch_bounds__(256) void wstats_part(
    const float* __restrict__ a0, const float* __restrict__ a1,
    const float* __restrict__ a2, const float* __restrict__ a3,
    const float* __restrict__ a4, const float* __restrict__ a5,
    const float* __restrict__ a6, double2* __restrict__ part,
    double2* __restrict__ stats) {
    int b = blockIdx.x;
    if      (b == 0) bstat(a0, 144,   stats + 0, 144);
    else if (b == 1) bstat(a1, 144,   stats + 1, 144);
    else if (b == 2) bstat(a2, 13824, stats + 2, 13824);
    else if (b == 3) bstat(a6, 5120,  stats + 6, 5120);
    else if (b < 8)  bstat(a3 + (b - 4)  * 12288, 12288, part + (b - 4), 0);
    else if (b < 24) bstat(a4 + (b - 8)  * 16384, 16384, part + 4 + (b - 8), 0);
    else             bstat(a5 + (b - 24) * 16384, 16384, part + 20 + (b - 24), 0);
}

__global__ __launch_bounds__(64) void wstats_comb(const double2* __restrict__ part,
                                                  double2* __restrict__ stats) {
    int t = threadIdx.x;
    if (t == 0) {
        double s = 0, a = 0;
        for (int i = 0; i < 4; i++) { s += part[i].x; a += part[i].y; }
        stats[3].x = s / 49152.0; stats[3].y = a / 49152.0;
    } else if (t == 1) {
        double s = 0, a = 0;
        for (int i = 4; i < 20; i++) { s += part[i].x; a += part[i].y; }
        stats[4].x = s / 262144.0; stats[4].y = a / 262144.0;
    } else if (t == 2) {
        double s = 0, a = 0;
        for (int i = 20; i < 36; i++) { s += part[i].x; a += part[i].y; }
        stats[5].x = s / 262144.0; stats[5].y = a / 262144.0;
    }
}

// ============ conv weights -> ODD integer levels ============
__device__ inline float q4odd(float w, double mag) {
    double sc = 2.0 / fmax(mag, EPSQ);
    double q = fmin(fmax(rint((double)w * sc - 0.5), -8.0), 7.0);
    return (float)(2.0 * q + 1.0);
}

// c1/c1b as f32 ints (used in f32 FMA); c2 as packed int8 (used in int dot)
__global__ __launch_bounds__(256) void wq_conv(
    const float* __restrict__ wc1, const float* __restrict__ wc1b,
    const float* __restrict__ wc2, const double2* __restrict__ stats,
    float* __restrict__ c1o, float* __restrict__ c1bo, char* __restrict__ c2i) {
    int i = blockIdx.x * 256 + threadIdx.x;
    if (i < 144) c1o[i] = q4odd(wc1[i], stats[0].y);
    else if (i < 288) c1bo[i - 144] = q4odd(wc1b[i - 144], stats[1].y);
    else if (i < 288 + 13824) {
        int j = i - 288;
        c2i[j] = (char)(int)q4odd(wc2[j], stats[2].y);
    }
}

// ============ fc weights: binary sign {-1,0,1} as int8 (f64 mean) ============
__device__ inline char bsign(float w, double mean) {
    double d = (double)w - mean;
    return d > 0.0 ? (char)1 : (d < 0.0 ? (char)-1 : (char)0);
}

__global__ __launch_bounds__(256) void wq_fc(
    const float* __restrict__ wfc1, const float* __restrict__ wfc2,
    const float* __restrict__ wfc3, const float* __restrict__ wfcl,
    const double2* __restrict__ stats,
    char* __restrict__ f1, char* __restrict__ f2,
    char* __restrict__ f3, char* __restrict__ fl) {
    int i = blockIdx.x * 256 + threadIdx.x;
    if (i < 65536) {                       // f1: [512][128] padded, K=96
        int row = i >> 7, k = i & 127;
        f1[i] = (k < 96) ? bsign(wfc1[row * 96 + k], stats[3].x) : (char)0;
        return;
    }
    i -= 65536;
    if (i < 262144) { f2[i] = bsign(wfc2[i], stats[4].x); return; }
    i -= 262144;
    if (i < 262144) { f3[i] = bsign(wfc3[i], stats[5].x); return; }
    i -= 262144;
    if (i < 5120)   { fl[i] = bsign(wfcl[i], stats[6].x); }
}

// exact int8x4 dot (values small -> all exact)
__device__ inline int bdot(int a, int b) {
    int r = ((a << 24) >> 24) * ((b << 24) >> 24);
    r += ((a << 16) >> 24) * ((b << 16) >> 24);
    r += ((a << 8) >> 24) * ((b << 8) >> 24);
    r += (a >> 24) * (b >> 24);
    return r;
}

// ============ exact integer 3-row pixel dot, f64 scale combine ============
template <int Wd>
__device__ inline double cpix(const float (&rq)[3][Wd], const float* wv,
                              const double* inv, int qx) {
    // products <= 127*15, sums <= 5715 < 2^24 -> fp32 arithmetic is EXACT
    float d0 = rq[0][qx] * wv[0] + rq[0][qx + 1] * wv[1] + rq[0][qx + 2] * wv[2];
    float d1 = rq[1][qx] * wv[3] + rq[1][qx + 1] * wv[4] + rq[1][qx + 2] * wv[5];
    float d2 = rq[2][qx] * wv[6] + rq[2][qx + 1] * wv[7] + rq[2][qx + 2] * wv[8];
    return (double)d0 * inv[0] + (double)d1 * inv[1] + (double)d2 * inv[2];
}

// ================= fused conv stack: one block per image =================
// v5: sh1/sh2 stored as packed u8 (exact small ints); conv1 reads sxp via
// ds_read_b128; conv2 is a pure int8 dot. All rounding decisions f64.
__global__ __launch_bounds__(256) void conv_fused(
    const float* __restrict__ x, const float* __restrict__ w1o,
    const float* __restrict__ w1bo, const char* __restrict__ w2i,
    const double2* __restrict__ stats,
    char* __restrict__ xq96, double* __restrict__ arow) {
    __shared__ float sxp[16][20];                 // f32 ints, b128-aligned rows
    __shared__ double sinv0[16];
    __shared__ unsigned int sh1[16][14][5];       // u8 x14 packed (4 dwords + pad)
    __shared__ double sinv1[16][14];
    __shared__ unsigned int sh2[16][12][3];       // u8 x12 packed
    __shared__ double sinv2[16][12];
    __shared__ float sw1[144], sw1b[144];
    __shared__ double sh3p[2][96];
    __shared__ double sh3[96];
    __shared__ double srs[2];
    int b = blockIdx.x, t = threadIdx.x;
    double cw1  = fmax(stats[0].y, EPSQ) * 0.25;
    double cw1b = fmax(stats[1].y, EPSQ) * 0.25;
    double cw2  = fmax(stats[2].y, EPSQ) * 0.25;

    // --- load + act_quant input (per row of 16) ---
    float v = x[(size_t)b * 256 + t];
    if (t < 144) { sw1[t] = w1o[t]; sw1b[t] = w1bo[t]; }
    float m = fabsf(v);
    for (int o = 8; o; o >>= 1) m = fmaxf(m, __shfl_xor(m, o));
    double s0 = 127.0 / fmax((double)m, EPSQ);
    sxp[t >> 4][t & 15] = (float)rint((double)v * s0);
    if ((t & 15) == 0) sinv0[t >> 4] = 1.0 / s0;
    __syncthreads();

    // --- conv1 3x3, 1->16ch, relu, act_quant rows of 14 ---
    if (t < 224) {
        int c = t / 14, r = t % 14;
        float rq[3][16]; double inv[3];
        #pragma unroll
        for (int i = 0; i < 3; i++) {
            inv[i] = sinv0[r + i] * cw1;
            #pragma unroll
            for (int q4 = 0; q4 < 4; q4++)
                *(float4*)&rq[i][q4 * 4] = *(const float4*)&sxp[r + i][q4 * 4];
        }
        float wv[9];
        #pragma unroll
        for (int k = 0; k < 9; k++) wv[k] = sw1[c * 9 + k];
        double vals[14]; double mx = 0.0;
        #pragma unroll
        for (int qx = 0; qx < 14; qx++) {
            vals[qx] = fmax(cpix(rq, wv, inv, qx), 0.0);
            mx = fmax(mx, vals[qx]);
        }
        double s2 = 127.0 / fmax(mx, EPSQ);
        sinv1[c][r] = 1.0 / s2;
        unsigned int pk[4] = {0u, 0u, 0u, 0u};
        #pragma unroll
        for (int qx = 0; qx < 14; qx++) {
            unsigned int q = (unsigned int)(int)rint(vals[qx] * s2);   // in [0,127]
            pk[qx >> 2] |= q << ((qx & 3) * 8);
        }
        #pragma unroll
        for (int j = 0; j < 4; j++) sh1[c][r][j] = pk[j];
    }
    __syncthreads();

    // --- depthwise 3x3, relu, act_quant rows of 12 ---
    if (t < 192) {
        int c = t / 12, r = t % 12;
        float rq[3][14]; double inv[3];
        #pragma unroll
        for (int i = 0; i < 3; i++) {
            inv[i] = sinv1[c][r + i] * cw1b;
            unsigned int w0 = sh1[c][r + i][0], w1 = sh1[c][r + i][1];
            unsigned int w2d = sh1[c][r + i][2], w3 = sh1[c][r + i][3];
            #pragma unroll
            for (int j = 0; j < 14; j++) {
                unsigned int wd = (j < 4) ? w0 : (j < 8) ? w1 : (j < 12) ? w2d : w3;
                rq[i][j] = (float)((wd >> ((j & 3) * 8)) & 0xffu);   // exact u8->f32
            }
        }
        float wv[9];
        #pragma unroll
        for (int k = 0; k < 9; k++) wv[k] = sw1b[c * 9 + k];
        double vals[12]; double mx = 0.0;
        #pragma unroll
        for (int qx = 0; qx < 12; qx++) {
            vals[qx] = fmax(cpix(rq, wv, inv, qx), 0.0);
            mx = fmax(mx, vals[qx]);
        }
        double s3 = 127.0 / fmax(mx, EPSQ);
        sinv2[c][r] = 1.0 / s3;
        unsigned int pk[3] = {0u, 0u, 0u};
        #pragma unroll
        for (int qx = 0; qx < 12; qx++) {
            unsigned int q = (unsigned int)(int)rint(vals[qx] * s3);
            pk[qx >> 2] |= q << ((qx & 3) * 8);
        }
        #pragma unroll
        for (int j = 0; j < 3; j++) sh2[c][r][j] = pk[j];
    }
    __syncthreads();

    // --- grouped conv2: int8 dot rows, f64 per-row combine ---
    if (t < 192) {
        int o = t % 96, half = t / 96;
        int g = o / 6;
        const int* wk = (const int*)(w2i + o * 144 + half * 72);
        double acc = 0.0;
        #pragma unroll
        for (int hh = 0; hh < 6; hh++) {
            int row = half * 6 + hh;
            int d = 0;
            #pragma unroll
            for (int j = 0; j < 3; j++)
                d += bdot((int)sh2[g][row][j], wk[hh * 3 + j]);
            acc += (double)d * sinv2[g][row];
        }
        sh3p[half][o] = acc;
    }
    __syncthreads();
    if (t < 96) sh3[t] = fmax((sh3p[0][t] + sh3p[1][t]) * cw2, 0.0);
    __syncthreads();

    // --- rmsnorm + act_quant over 96, f64 ---
    if (t < 64) {
        double a = sh3[t];
        double bb = (t < 32) ? sh3[64 + t] : 0.0;
        double ss = a * a + bb * bb;
        double mxx = fmax(fabs(a), fabs(bb));
        for (int o = 32; o; o >>= 1) {
            ss += __shfl_down(ss, o);
            mxx = fmax(mxx, __shfl_down(mxx, o));
        }
        if (t == 0) {
            double r = 1.0 / sqrt(ss / 96.0 + 1e-5);
            double s4 = 127.0 / fmax(mxx * r, EPSQ);
            srs[0] = r; srs[1] = s4;
        }
    }
    __syncthreads();
    if (t < 128) {
        char q = 0;
        if (t < 96) {
            double xn = sh3[t] * srs[0];
            q = (char)(int)rint(xn * srs[1]);
        }
        xq96[(size_t)b * 128 + t] = q;
        if (t == 0) arow[b] = 1.0 / srs[1];
    }
}

// ======= fused FC layer: xq_out = act_quant(rmsnorm(relu(Xq·Wq^T))) =======
// v2: BM=64, BN=512, BK=128; 4 waves, each owns 128 cols x 64 rows (acc[2][4]).
__global__ __launch_bounds__(256, 2) void fc_fused(
    const char* __restrict__ Xq, const char* __restrict__ Wq, int K,
    const double2* __restrict__ stats, int sidx,
    double* __restrict__ arow, char* __restrict__ xq) {
    __shared__ char As[64 * 128];
    __shared__ char Bs[512 * 128];
    __shared__ double redS[4][64];
    __shared__ int    redM[4][64];
    __shared__ double csrow[64];
    int t = threadIdx.x;
    int lane = t & 63;
    int w = t >> 6;
    int m0 = blockIdx.x * 64;

    v16i acc[2][4] = {};

    for (int k0 = 0; k0 < K; k0 += 128) {
        #pragma unroll
        for (int p = 0; p < 2; p++) {
            int slot = p * 256 + t;
            int row = slot >> 3, cb = (slot & 7) * 16;
            *(int4*)(As + row * 128 + (cb ^ ((row & 7) << 4))) =
                *(const int4*)(Xq + (size_t)(m0 + row) * K + k0 + cb);
        }
        #pragma unroll
        for (int p = 0; p < 16; p++) {
            int slot = p * 256 + t;
            int row = slot >> 3, cb = (slot & 7) * 16;
            *(int4*)(Bs + row * 128 + (cb ^ ((row & 7) << 4))) =
                *(const int4*)(Wq + (size_t)row * K + k0 + cb);
        }
        __syncthreads();
        int ksel = (lane >> 5) * 16;
        int ra0 = lane & 31, ra1 = 32 + (lane & 31);
        #pragma unroll
        for (int kk = 0; kk < 4; kk++) {
            int kb = kk * 32 + ksel;
            v4i a0 = *(v4i*)(As + ra0 * 128 + (kb ^ ((ra0 & 7) << 4)));
            v4i a1 = *(v4i*)(As + ra1 * 128 + (kb ^ ((ra1 & 7) << 4)));
            #pragma unroll
            for (int nt = 0; nt < 4; nt++) {
                int rb = w * 128 + nt * 32 + (lane & 31);
                v4i bb = *(v4i*)(Bs + rb * 128 + (kb ^ ((rb & 7) << 4)));
                acc[0][nt] = __builtin_amdgcn_mfma_i32_32x32x32_i8(a0, bb, acc[0][nt], 0, 0, 0);
                acc[1][nt] = __builtin_amdgcn_mfma_i32_32x32x32_i8(a1, bb, acc[1][nt], 0, 0, 0);
            }
        }
        __syncthreads();
    }

    // --- relu (exact) + per-row sumsq (f64) / max (int) ---
    #pragma unroll
    for (int mt = 0; mt < 2; mt++) {
        double ps[16]; int pm[16];
        #pragma unroll
        for (int reg = 0; reg < 16; reg++) {
            int v0 = max(acc[mt][0][reg], 0), v1 = max(acc[mt][1][reg], 0);
            int v2 = max(acc[mt][2][reg], 0), v3 = max(acc[mt][3][reg], 0);
            acc[mt][0][reg] = v0; acc[mt][1][reg] = v1;
            acc[mt][2][reg] = v2; acc[mt][3][reg] = v3;
            ps[reg] = (double)v0 * v0 + (double)v1 * v1 + (double)v2 * v2 + (double)v3 * v3;
            pm[reg] = max(max(v0, v1), max(v2, v3));
        }
        #pragma unroll
        for (int o = 1; o < 32; o <<= 1)
            #pragma unroll
            for (int reg = 0; reg < 16; reg++) {
                ps[reg] += __shfl_xor(ps[reg], o);
                pm[reg] = max(pm[reg], __shfl_xor(pm[reg], o));
            }
        if ((lane & 31) == 0) {
            int h = lane >> 5;
            #pragma unroll
            for (int reg = 0; reg < 16; reg++) {
                int row = mt * 32 + (reg & 3) + 8 * (reg >> 2) + 4 * h;
                redS[w][row] = ps[reg];
                redM[w][row] = pm[reg];
            }
        }
    }
    __syncthreads();
    if (t < 64) {
        double S = redS[0][t] + redS[1][t] + redS[2][t] + redS[3][t];
        int M = max(max(redM[0][t], redM[1][t]), max(redM[2][t], redM[3][t]));
        double c = stats[sidx].y * arow[m0 + t];
        double mean = S * c * c / 512.0;
        double r = 1.0 / sqrt(mean + 1e-5);
        double s = 127.0 / fmax((double)M * c * r, EPSQ);
        csrow[t] = c * r * s;
        arow[m0 + t] = 1.0 / s;
    }
    __syncthreads();

    // --- quantize into Bs as [64][512] bytes, then vector copy out ---
    #pragma unroll
    for (int mt = 0; mt < 2; mt++)
        #pragma unroll
        for (int nt = 0; nt < 4; nt++) {
            int col = w * 128 + nt * 32 + (lane & 31);
            #pragma unroll
            for (int reg = 0; reg < 16; reg++) {
                int row = mt * 32 + (reg & 3) + 8 * (reg >> 2) + 4 * (lane >> 5);
                Bs[row * 512 + col] = (char)(int)rint((double)acc[mt][nt][reg] * csrow[row]);
            }
        }
    __syncthreads();
    #pragma unroll
    for (int i = 0; i < 8; i++) {
        int idx = i * 256 + t;
        *(int4*)(xq + (size_t)m0 * 512 + idx * 16) = *(const int4*)(Bs + idx * 16);
    }
}

// ================= final layer: N=10, exact int dot =================
__global__ __launch_bounds__(256) void fcl_k(const char* __restrict__ Xq,
                                             const char* __restrict__ Wq,
                                             const double* __restrict__ arow,
                                             const double2* __restrict__ stats,
                                             float* __restrict__ out) {
    int gi = blockIdx.x * 256 + threadIdx.x;     // 163840 = 16384*10 exact
    int mrow = gi / 10, n = gi - mrow * 10;
    const int4* xp = (const int4*)(Xq + (size_t)mrow * 512);
    const int4* wp = (const int4*)(Wq + n * 512);
    int acc = 0;
    #pragma unroll 8
    for (int i = 0; i < 32; i++) {
        int4 a = xp[i], b = wp[i];
        acc += bdot(a.x, b.x) + bdot(a.y, b.y) + bdot(a.z, b.z) + bdot(a.w, b.w);
    }
    out[gi] = (float)((double)acc * stats[6].y * arow[mrow]);
}

// ================= launcher =================
extern "C" void kernel_launch(void* const* d_in, const int* in_sizes, int n_in,
                              void* d_out, int out_size, void* d_ws, size_t ws_size,
                              hipStream_t stream) {
    const float* x     = (const float*)d_in[0];
    const float* w_c1  = (const float*)d_in[1];
    const float* w_c1b = (const float*)d_in[2];
    const float* w_c2  = (const float*)d_in[3];
    const float* w_fc1 = (const float*)d_in[4];
    const float* w_fc2 = (const float*)d_in[5];
    const float* w_fc3 = (const float*)d_in[6];
    const float* w_fcl = (const float*)d_in[7];
    float* out = (float*)d_out;
    char* wsb = (char*)d_ws;
    const int B = 16384;

    // ws layout (byte offsets, 16B-aligned)
    float*   c1o   = (float*)(wsb + 0);          // 576 B
    float*   c1bo  = (float*)(wsb + 1024);       // 576 B
    char*    c2i   = wsb + 2048;                 // 13824 B (int8)
    double2* stats = (double2*)(wsb + 57344);    // 112 B
    double2* part  = (double2*)(wsb + 57856);    // 576 B
    char*    f1q   = wsb + 65536;                // 512*128
    char*    f2q   = wsb + 131072;               // 512*512
    char*    f3q   = wsb + 393216;               // 512*512
    char*    flq   = wsb + 655360;               // 10*512
    double*  arow  = (double*)(wsb + 663552);    // B doubles
    char*    xq96  = wsb + 1048576;              // B*128
    char*    xq512 = wsb + 3145728;              // B*512 (end ~11.5 MB)

    // --- weight stats + quantization ---
    wstats_part<<<40, 256, 0, stream>>>(w_c1, w_c1b, w_c2, w_fc1, w_fc2, w_fc3,
                                        w_fcl, part, stats);
    wstats_comb<<<1, 64, 0, stream>>>(part, stats);
    wq_conv<<<56, 256, 0, stream>>>(w_c1, w_c1b, w_c2, stats, c1o, c1bo, c2i);
    wq_fc<<<2324, 256, 0, stream>>>(w_fc1, w_fc2, w_fc3, w_fcl, stats, f1q, f2q, f3q, flq);

    // --- conv stack -> int8 [B,128] + f64 arow ---
    conv_fused<<<B, 256, 0, stream>>>(x, c1o, c1bo, c2i, stats, xq96, arow);

    // --- fused FC layers (gemm + relu + rmsnorm + act_quant each) ---
    fc_fused<<<B / 64, 256, 0, stream>>>(xq96,  f1q, 128, stats, 3, arow, xq512);
    fc_fused<<<B / 64, 256, 0, stream>>>(xq512, f2q, 512, stats, 4, arow, xq512);
    fc_fused<<<B / 64, 256, 0, stream>>>(xq512, f3q, 512, stats, 5, arow, xq512);

    // --- fcl ---
    fcl_k<<<640, 256, 0, stream>>>(xq512, flq, arow, stats, out);
}

// Round 12
// 247.326 us; speedup vs baseline: 1.3766x; 1.3766x over previous
//
#include <hip/hip_runtime.h>
#include <math.h>

#define EPSQ 1e-5

typedef int v4i  __attribute__((ext_vector_type(4)));
typedef int v16i __attribute__((ext_vector_type(16)));

// ================= weight stats: partial sums, f64 =================
__device__ void bstat(const float* __restrict__ w, int cnt, double2* dst, int divn) {
    __shared__ double ls[4], la[4];
    int t = threadIdx.x;
    double s = 0.0, a = 0.0;
    const float4* w4 = (const float4*)w;
    int nv = cnt >> 2;
    for (int i = t; i < nv; i += 256) {
        float4 v = w4[i];
        s += (double)v.x + (double)v.y + (double)v.z + (double)v.w;
        a += fabs((double)v.x) + fabs((double)v.y) + fabs((double)v.z) + fabs((double)v.w);
    }
    for (int o = 32; o; o >>= 1) { s += __shfl_down(s, o); a += __shfl_down(a, o); }
    if ((t & 63) == 0) { ls[t >> 6] = s; la[t >> 6] = a; }
    __syncthreads();
    if (t == 0) {
        for (int i = 1; i < 4; i++) { s += ls[i]; a += la[i]; }
        if (divn > 0) { dst->x = s / divn; dst->y = a / divn; }
        else          { dst->x = s;        dst->y = a; }
    }
}

// grid = 40 blocks: 0:c1 1:c1b 2:c2 3:fcl | 4-7:fc1/4 | 8-23:fc2/16 | 24-39:fc3/16
__global__ __launch_bounds__(256) void wstats_part(
    const float* __restrict__ a0, const float* __restrict__ a1,
    const float* __restrict__ a2, const float* __restrict__ a3,
    const float* __restrict__ a4, const float* __restrict__ a5,
    const float* __restrict__ a6, double2* __restrict__ part,
    double2* __restrict__ stats) {
    int b = blockIdx.x;
    if      (b == 0) bstat(a0, 144,   stats + 0, 144);
    else if (b == 1) bstat(a1, 144,   stats + 1, 144);
    else if (b == 2) bstat(a2, 13824, stats + 2, 13824);
    else if (b == 3) bstat(a6, 5120,  stats + 6, 5120);
    else if (b < 8)  bstat(a3 + (b - 4)  * 12288, 12288, part + (b - 4), 0);
    else if (b < 24) bstat(a4 + (b - 8)  * 16384, 16384, part + 4 + (b - 8), 0);
    else             bstat(a5 + (b - 24) * 16384, 16384, part + 20 + (b - 24), 0);
}

__global__ __launch_bounds__(64) void wstats_comb(const double2* __restrict__ part,
                                                  double2* __restrict__ stats) {
    int t = threadIdx.x;
    if (t == 0) {
        double s = 0, a = 0;
        for (int i = 0; i < 4; i++) { s += part[i].x; a += part[i].y; }
        stats[3].x = s / 49152.0; stats[3].y = a / 49152.0;
    } else if (t == 1) {
        double s = 0, a = 0;
        for (int i = 4; i < 20; i++) { s += part[i].x; a += part[i].y; }
        stats[4].x = s / 262144.0; stats[4].y = a / 262144.0;
    } else if (t == 2) {
        double s = 0, a = 0;
        for (int i = 20; i < 36; i++) { s += part[i].x; a += part[i].y; }
        stats[5].x = s / 262144.0; stats[5].y = a / 262144.0;
    }
}

// ============ conv weights -> ODD integer levels ============
__device__ inline float q4odd(float w, double mag) {
    double sc = 2.0 / fmax(mag, EPSQ);
    double q = fmin(fmax(rint((double)w * sc - 0.5), -8.0), 7.0);
    return (float)(2.0 * q + 1.0);
}

// c1/c1b as f32 ints (used in f32 FMA); c2 as packed int8 (used in int dot)
__global__ __launch_bounds__(256) void wq_conv(
    const float* __restrict__ wc1, const float* __restrict__ wc1b,
    const float* __restrict__ wc2, const double2* __restrict__ stats,
    float* __restrict__ c1o, float* __restrict__ c1bo, char* __restrict__ c2i) {
    int i = blockIdx.x * 256 + threadIdx.x;
    if (i < 144) c1o[i] = q4odd(wc1[i], stats[0].y);
    else if (i < 288) c1bo[i - 144] = q4odd(wc1b[i - 144], stats[1].y);
    else if (i < 288 + 13824) {
        int j = i - 288;
        c2i[j] = (char)(int)q4odd(wc2[j], stats[2].y);
    }
}

// ============ fc weights: binary sign {-1,0,1} as int8 (f64 mean) ============
__device__ inline char bsign(float w, double mean) {
    double d = (double)w - mean;
    return d > 0.0 ? (char)1 : (d < 0.0 ? (char)-1 : (char)0);
}

__global__ __launch_bounds__(256) void wq_fc(
    const float* __restrict__ wfc1, const float* __restrict__ wfc2,
    const float* __restrict__ wfc3, const float* __restrict__ wfcl,
    const double2* __restrict__ stats,
    char* __restrict__ f1, char* __restrict__ f2,
    char* __restrict__ f3, char* __restrict__ fl) {
    int i = blockIdx.x * 256 + threadIdx.x;
    if (i < 65536) {                       // f1: [512][128] padded, K=96
        int row = i >> 7, k = i & 127;
        f1[i] = (k < 96) ? bsign(wfc1[row * 96 + k], stats[3].x) : (char)0;
        return;
    }
    i -= 65536;
    if (i < 262144) { f2[i] = bsign(wfc2[i], stats[4].x); return; }
    i -= 262144;
    if (i < 262144) { f3[i] = bsign(wfc3[i], stats[5].x); return; }
    i -= 262144;
    if (i < 5120)   { fl[i] = bsign(wfcl[i], stats[6].x); }
}

// exact int8x4 dot (values small -> all exact)
__device__ inline int bdot(int a, int b) {
    int r = ((a << 24) >> 24) * ((b << 24) >> 24);
    r += ((a << 16) >> 24) * ((b << 16) >> 24);
    r += ((a << 8) >> 24) * ((b << 8) >> 24);
    r += (a >> 24) * (b >> 24);
    return r;
}

// ============ exact integer 3-row pixel dot, f64 scale combine ============
template <int Wd>
__device__ inline double cpix(const float (&rq)[3][Wd], const float* wv,
                              const double* inv, int qx) {
    // products <= 127*15, sums <= 5715 < 2^24 -> fp32 arithmetic is EXACT
    float d0 = rq[0][qx] * wv[0] + rq[0][qx + 1] * wv[1] + rq[0][qx + 2] * wv[2];
    float d1 = rq[1][qx] * wv[3] + rq[1][qx + 1] * wv[4] + rq[1][qx + 2] * wv[5];
    float d2 = rq[2][qx] * wv[6] + rq[2][qx + 1] * wv[7] + rq[2][qx + 2] * wv[8];
    return (double)d0 * inv[0] + (double)d1 * inv[1] + (double)d2 * inv[2];
}

// ================= fused conv stack: one block per image =================
// v5 (unchanged from r10): packed-u8 LDS, int8 conv2 dot, f64 decisions.
__global__ __launch_bounds__(256) void conv_fused(
    const float* __restrict__ x, const float* __restrict__ w1o,
    const float* __restrict__ w1bo, const char* __restrict__ w2i,
    const double2* __restrict__ stats,
    char* __restrict__ xq96, double* __restrict__ arow) {
    __shared__ float sxp[16][20];                 // f32 ints, b128-aligned rows
    __shared__ double sinv0[16];
    __shared__ unsigned int sh1[16][14][5];       // u8 x14 packed (4 dwords + pad)
    __shared__ double sinv1[16][14];
    __shared__ unsigned int sh2[16][12][3];       // u8 x12 packed
    __shared__ double sinv2[16][12];
    __shared__ float sw1[144], sw1b[144];
    __shared__ double sh3p[2][96];
    __shared__ double sh3[96];
    __shared__ double srs[2];
    int b = blockIdx.x, t = threadIdx.x;
    double cw1  = fmax(stats[0].y, EPSQ) * 0.25;
    double cw1b = fmax(stats[1].y, EPSQ) * 0.25;
    double cw2  = fmax(stats[2].y, EPSQ) * 0.25;

    // --- load + act_quant input (per row of 16) ---
    float v = x[(size_t)b * 256 + t];
    if (t < 144) { sw1[t] = w1o[t]; sw1b[t] = w1bo[t]; }
    float m = fabsf(v);
    for (int o = 8; o; o >>= 1) m = fmaxf(m, __shfl_xor(m, o));
    double s0 = 127.0 / fmax((double)m, EPSQ);
    sxp[t >> 4][t & 15] = (float)rint((double)v * s0);
    if ((t & 15) == 0) sinv0[t >> 4] = 1.0 / s0;
    __syncthreads();

    // --- conv1 3x3, 1->16ch, relu, act_quant rows of 14 ---
    if (t < 224) {
        int c = t / 14, r = t % 14;
        float rq[3][16]; double inv[3];
        #pragma unroll
        for (int i = 0; i < 3; i++) {
            inv[i] = sinv0[r + i] * cw1;
            #pragma unroll
            for (int q4 = 0; q4 < 4; q4++)
                *(float4*)&rq[i][q4 * 4] = *(const float4*)&sxp[r + i][q4 * 4];
        }
        float wv[9];
        #pragma unroll
        for (int k = 0; k < 9; k++) wv[k] = sw1[c * 9 + k];
        double vals[14]; double mx = 0.0;
        #pragma unroll
        for (int qx = 0; qx < 14; qx++) {
            vals[qx] = fmax(cpix(rq, wv, inv, qx), 0.0);
            mx = fmax(mx, vals[qx]);
        }
        double s2 = 127.0 / fmax(mx, EPSQ);
        sinv1[c][r] = 1.0 / s2;
        unsigned int pk[4] = {0u, 0u, 0u, 0u};
        #pragma unroll
        for (int qx = 0; qx < 14; qx++) {
            unsigned int q = (unsigned int)(int)rint(vals[qx] * s2);   // in [0,127]
            pk[qx >> 2] |= q << ((qx & 3) * 8);
        }
        #pragma unroll
        for (int j = 0; j < 4; j++) sh1[c][r][j] = pk[j];
    }
    __syncthreads();

    // --- depthwise 3x3, relu, act_quant rows of 12 ---
    if (t < 192) {
        int c = t / 12, r = t % 12;
        float rq[3][14]; double inv[3];
        #pragma unroll
        for (int i = 0; i < 3; i++) {
            inv[i] = sinv1[c][r + i] * cw1b;
            unsigned int w0 = sh1[c][r + i][0], w1 = sh1[c][r + i][1];
            unsigned int w2d = sh1[c][r + i][2], w3 = sh1[c][r + i][3];
            #pragma unroll
            for (int j = 0; j < 14; j++) {
                unsigned int wd = (j < 4) ? w0 : (j < 8) ? w1 : (j < 12) ? w2d : w3;
                rq[i][j] = (float)((wd >> ((j & 3) * 8)) & 0xffu);   // exact u8->f32
            }
        }
        float wv[9];
        #pragma unroll
        for (int k = 0; k < 9; k++) wv[k] = sw1b[c * 9 + k];
        double vals[12]; double mx = 0.0;
        #pragma unroll
        for (int qx = 0; qx < 12; qx++) {
            vals[qx] = fmax(cpix(rq, wv, inv, qx), 0.0);
            mx = fmax(mx, vals[qx]);
        }
        double s3 = 127.0 / fmax(mx, EPSQ);
        sinv2[c][r] = 1.0 / s3;
        unsigned int pk[3] = {0u, 0u, 0u};
        #pragma unroll
        for (int qx = 0; qx < 12; qx++) {
            unsigned int q = (unsigned int)(int)rint(vals[qx] * s3);
            pk[qx >> 2] |= q << ((qx & 3) * 8);
        }
        #pragma unroll
        for (int j = 0; j < 3; j++) sh2[c][r][j] = pk[j];
    }
    __syncthreads();

    // --- grouped conv2: int8 dot rows, f64 per-row combine ---
    if (t < 192) {
        int o = t % 96, half = t / 96;
        int g = o / 6;
        const int* wk = (const int*)(w2i + o * 144 + half * 72);
        double acc = 0.0;
        #pragma unroll
        for (int hh = 0; hh < 6; hh++) {
            int row = half * 6 + hh;
            int d = 0;
            #pragma unroll
            for (int j = 0; j < 3; j++)
                d += bdot((int)sh2[g][row][j], wk[hh * 3 + j]);
            acc += (double)d * sinv2[g][row];
        }
        sh3p[half][o] = acc;
    }
    __syncthreads();
    if (t < 96) sh3[t] = fmax((sh3p[0][t] + sh3p[1][t]) * cw2, 0.0);
    __syncthreads();

    // --- rmsnorm + act_quant over 96, f64 ---
    if (t < 64) {
        double a = sh3[t];
        double bb = (t < 32) ? sh3[64 + t] : 0.0;
        double ss = a * a + bb * bb;
        double mxx = fmax(fabs(a), fabs(bb));
        for (int o = 32; o; o >>= 1) {
            ss += __shfl_down(ss, o);
            mxx = fmax(mxx, __shfl_down(mxx, o));
        }
        if (t == 0) {
            double r = 1.0 / sqrt(ss / 96.0 + 1e-5);
            double s4 = 127.0 / fmax(mxx * r, EPSQ);
            srs[0] = r; srs[1] = s4;
        }
    }
    __syncthreads();
    if (t < 128) {
        char q = 0;
        if (t < 96) {
            double xn = sh3[t] * srs[0];
            q = (char)(int)rint(xn * srs[1]);
        }
        xq96[(size_t)b * 128 + t] = q;
        if (t == 0) arow[b] = 1.0 / srs[1];
    }
}

// ======= fused FC layer: xq_out = act_quant(rmsnorm(relu(Xq·Wq^T))) =======
// v3: BM=32 (512 blocks, 2/CU — the measured-good config) + global_load_lds
// staging with PRE-SWIZZLED SOURCE (linear LDS dest, XOR on global addr and
// on ds_read — involution, rule #21). Halves staging instruction count.
__global__ __launch_bounds__(256, 2) void fc_fused(
    const char* __restrict__ Xq, const char* __restrict__ Wq, int K,
    const double2* __restrict__ stats, int sidx,
    double* __restrict__ arow, char* __restrict__ xq) {
    __shared__ char As[32 * 128];
    __shared__ char Bs[512 * 128];
    __shared__ double redS[4][32];
    __shared__ int    redM[4][32];
    __shared__ double csrow[32];
    int t = threadIdx.x;
    int lane = t & 63;
    int w = t >> 6;
    int m0 = blockIdx.x * 32;

    v16i acc[4] = {};

    for (int k0 = 0; k0 < K; k0 += 128) {
        // ---- As: 4 KB = 4 chunks of 1024 B; wave w stages chunk w ----
        {
            int a = w * 1024 + lane * 16;
            int row = a >> 7, c = a & 127;
            const char* src = Xq + (size_t)(m0 + row) * K + k0 + (c ^ ((row & 7) << 4));
            __builtin_amdgcn_global_load_lds(
                (const __attribute__((address_space(1))) void*)src,
                (__attribute__((address_space(3))) void*)(As + a), 16, 0, 0);
        }
        // ---- Bs: 64 KB = 64 chunks; wave w stages chunks i*4+w ----
        #pragma unroll
        for (int i = 0; i < 16; i++) {
            int a = (i * 4 + w) * 1024 + lane * 16;
            int row = a >> 7, c = a & 127;
            const char* src = Wq + (size_t)row * K + k0 + (c ^ ((row & 7) << 4));
            __builtin_amdgcn_global_load_lds(
                (const __attribute__((address_space(1))) void*)src,
                (__attribute__((address_space(3))) void*)(Bs + a), 16, 0, 0);
        }
        __syncthreads();
        int ra = lane & 31;
        int ksel = (lane >> 5) * 16;
        #pragma unroll
        for (int kk = 0; kk < 4; kk++) {
            int kb = kk * 32 + ksel;
            v4i a = *(v4i*)(As + ra * 128 + (kb ^ ((ra & 7) << 4)));
            #pragma unroll
            for (int nt = 0; nt < 4; nt++) {
                int rb = w * 128 + nt * 32 + (lane & 31);
                v4i bb = *(v4i*)(Bs + rb * 128 + (kb ^ ((rb & 7) << 4)));
                acc[nt] = __builtin_amdgcn_mfma_i32_32x32x32_i8(a, bb, acc[nt], 0, 0, 0);
            }
        }
        __syncthreads();
    }

    // --- relu (exact) + per-row sumsq (f64) and max (int), 32-lane butterfly ---
    double ps[16]; int pm[16];
    #pragma unroll
    for (int reg = 0; reg < 16; reg++) {
        int v0 = max(acc[0][reg], 0), v1 = max(acc[1][reg], 0);
        int v2 = max(acc[2][reg], 0), v3 = max(acc[3][reg], 0);
        acc[0][reg] = v0; acc[1][reg] = v1; acc[2][reg] = v2; acc[3][reg] = v3;
        ps[reg] = (double)v0 * v0 + (double)v1 * v1 + (double)v2 * v2 + (double)v3 * v3;
        pm[reg] = max(max(v0, v1), max(v2, v3));
    }
    #pragma unroll
    for (int o = 1; o < 32; o <<= 1) {
        #pragma unroll
        for (int reg = 0; reg < 16; reg++) {
            ps[reg] += __shfl_xor(ps[reg], o);
            pm[reg] = max(pm[reg], __shfl_xor(pm[reg], o));
        }
    }
    if ((lane & 31) == 0) {
        int h = lane >> 5;
        #pragma unroll
        for (int reg = 0; reg < 16; reg++) {
            int row = (reg & 3) + 8 * (reg >> 2) + 4 * h;
            redS[w][row] = ps[reg];
            redM[w][row] = pm[reg];
        }
    }
    __syncthreads();
    if (t < 32) {
        double S = redS[0][t] + redS[1][t] + redS[2][t] + redS[3][t];
        int M = max(max(redM[0][t], redM[1][t]), max(redM[2][t], redM[3][t]));
        double c = stats[sidx].y * arow[m0 + t];
        double mean = S * c * c / 512.0;
        double r = 1.0 / sqrt(mean + 1e-5);
        double s = 127.0 / fmax((double)M * c * r, EPSQ);
        csrow[t] = c * r * s;
        arow[m0 + t] = 1.0 / s;
    }
    __syncthreads();

    // --- quantize (values in [0,127]) into Bs as [32][512] bytes, copy out ---
    #pragma unroll
    for (int nt = 0; nt < 4; nt++) {
        int col = w * 128 + nt * 32 + (lane & 31);
        #pragma unroll
        for (int reg = 0; reg < 16; reg++) {
            int row = (reg & 3) + 8 * (reg >> 2) + 4 * (lane >> 5);
            Bs[row * 512 + col] = (char)(int)rint((double)acc[nt][reg] * csrow[row]);
        }
    }
    __syncthreads();
    #pragma unroll
    for (int i = 0; i < 4; i++) {
        int idx = i * 256 + t;
        *(int4*)(xq + (size_t)m0 * 512 + idx * 16) = *(const int4*)(Bs + idx * 16);
    }
}

// ================= final layer: N=10, exact int dot =================
__global__ __launch_bounds__(256) void fcl_k(const char* __restrict__ Xq,
                                             const char* __restrict__ Wq,
                                             const double* __restrict__ arow,
                                             const double2* __restrict__ stats,
                                             float* __restrict__ out) {
    int gi = blockIdx.x * 256 + threadIdx.x;     // 163840 = 16384*10 exact
    int mrow = gi / 10, n = gi - mrow * 10;
    const int4* xp = (const int4*)(Xq + (size_t)mrow * 512);
    const int4* wp = (const int4*)(Wq + n * 512);
    int acc = 0;
    #pragma unroll 8
    for (int i = 0; i < 32; i++) {
        int4 a = xp[i], b = wp[i];
        acc += bdot(a.x, b.x) + bdot(a.y, b.y) + bdot(a.z, b.z) + bdot(a.w, b.w);
    }
    out[gi] = (float)((double)acc * stats[6].y * arow[mrow]);
}

// ================= launcher =================
extern "C" void kernel_launch(void* const* d_in, const int* in_sizes, int n_in,
                              void* d_out, int out_size, void* d_ws, size_t ws_size,
                              hipStream_t stream) {
    const float* x     = (const float*)d_in[0];
    const float* w_c1  = (const float*)d_in[1];
    const float* w_c1b = (const float*)d_in[2];
    const float* w_c2  = (const float*)d_in[3];
    const float* w_fc1 = (const float*)d_in[4];
    const float* w_fc2 = (const float*)d_in[5];
    const float* w_fc3 = (const float*)d_in[6];
    const float* w_fcl = (const float*)d_in[7];
    float* out = (float*)d_out;
    char* wsb = (char*)d_ws;
    const int B = 16384;

    // ws layout (byte offsets, 16B-aligned)
    float*   c1o   = (float*)(wsb + 0);          // 576 B
    float*   c1bo  = (float*)(wsb + 1024);       // 576 B
    char*    c2i   = wsb + 2048;                 // 13824 B (int8)
    double2* stats = (double2*)(wsb + 57344);    // 112 B
    double2* part  = (double2*)(wsb + 57856);    // 576 B
    char*    f1q   = wsb + 65536;                // 512*128
    char*    f2q   = wsb + 131072;               // 512*512
    char*    f3q   = wsb + 393216;               // 512*512
    char*    flq   = wsb + 655360;               // 10*512
    double*  arow  = (double*)(wsb + 663552);    // B doubles
    char*    xq96  = wsb + 1048576;              // B*128
    char*    xq512 = wsb + 3145728;              // B*512 (end ~11.5 MB)

    // --- weight stats + quantization ---
    wstats_part<<<40, 256, 0, stream>>>(w_c1, w_c1b, w_c2, w_fc1, w_fc2, w_fc3,
                                        w_fcl, part, stats);
    wstats_comb<<<1, 64, 0, stream>>>(part, stats);
    wq_conv<<<56, 256, 0, stream>>>(w_c1, w_c1b, w_c2, stats, c1o, c1bo, c2i);
    wq_fc<<<2324, 256, 0, stream>>>(w_fc1, w_fc2, w_fc3, w_fcl, stats, f1q, f2q, f3q, flq);

    // --- conv stack -> int8 [B,128] + f64 arow ---
    conv_fused<<<B, 256, 0, stream>>>(x, c1o, c1bo, c2i, stats, xq96, arow);

    // --- fused FC layers (gemm + relu + rmsnorm + act_quant each) ---
    fc_fused<<<B / 32, 256, 0, stream>>>(xq96,  f1q, 128, stats, 3, arow, xq512);
    fc_fused<<<B / 32, 256, 0, stream>>>(xq512, f2q, 512, stats, 4, arow, xq512);
    fc_fused<<<B / 32, 256, 0, stream>>>(xq512, f3q, 512, stats, 5, arow, xq512);

    // --- fcl ---
    fcl_k<<<640, 256, 0, stream>>>(xq512, flq, arow, stats, out);
}